// Round 3
// baseline (18891.719 us; speedup 1.0000x reference)
//
#include <hip/hip_runtime.h>
#include <hip/hip_bf16.h>
#include <cstdint>
#include <cstddef>

// Swin block: B=32 H=W=56 C=384 NH=12 HD=32 WS=7 SS=3 N=49 NW=64 Bn=2048 HID=1536
// M = 100352 tokens.  ALL inputs/outputs are FLOAT32 (per reference).
// Internals: bf16 storage, f32 accumulation.
//
// d_out (f32, 154,140,672 B) doubles as scratch:
//   H0 = bytes [0, 77070336)         : attnout bf16 (100352x384)  [dead after proj]
//   H1 = bytes [77070336, 154140672) : xmid bf16 (100352x384)     [residual after attn]
// Final f32 output overwrites d_out chunk-by-chunk; hazard-free schedule (see launch).
//
// ws layout (49,774,592 B):
//   [0,        802816)   ln1 stats (mean,rstd f32 per token, x-layout)
//   [802816,   1605632)  ln2 stats
//   [1605632,  11239424) resbuf  bf16 12544x384  (per-chunk copy of xmid rows)
//   [11239424, 49774592) hbuf    bf16 12544x1536 (fc1 output chunk)

__device__ __forceinline__ float bf2f(__hip_bfloat16 x) { return __bfloat162float(x); }
__device__ __forceinline__ __hip_bfloat16 f2bf(float x) { return __float2bfloat16(x); }
__device__ __forceinline__ float gelu_exact(float x) {
    return 0.5f * x * (1.0f + erff(x * 0.70710678118654752f));
}

// ---------------- LN stats: per token mean/rstd over 384 channels ----------------
template<typename T>
__global__ __launch_bounds__(256)
void ln_stats_kernel(const T* __restrict__ src, float* __restrict__ stats)
{
    int t = blockIdx.x * 4 + (threadIdx.x >> 6);
    int lane = threadIdx.x & 63;
    const T* p = src + (size_t)t * 384;
    float s = 0.f, s2 = 0.f;
#pragma unroll
    for (int u = 0; u < 6; ++u) {
        float f;
        if constexpr (sizeof(T) == 2) f = bf2f(*(const __hip_bfloat16*)&p[lane * 6 + u]);
        else                          f = (float)p[lane * 6 + u];
        s += f; s2 += f * f;
    }
#pragma unroll
    for (int off = 32; off > 0; off >>= 1) {
        s  += __shfl_xor(s, off);
        s2 += __shfl_xor(s2, off);
    }
    if (lane == 0) {
        float mean = s * (1.f / 384.f);
        float var  = fmaxf(s2 * (1.f / 384.f) - mean * mean, 0.f);
        stats[2 * t]     = mean;
        stats[2 * t + 1] = rsqrtf(var + 1e-5f);
    }
}

// ---------------- K2: fused LN1+gather + qkv + attention per (window, head) ------
__global__ __launch_bounds__(256)
void attn_kernel(const float* __restrict__ x,
                 const float* __restrict__ ln1s,     // (mean,rstd) per x-layout token
                 const float* __restrict__ ln1_g,
                 const float* __restrict__ ln1_b,
                 const float* __restrict__ qkv_w,    // 384 x 1152
                 const float* __restrict__ qkv_b,    // 1152
                 const float* __restrict__ rel_bias, // 169 x 12
                 __hip_bfloat16* __restrict__ attn_out)  // (100352, 384) bf16
{
    const int bi = blockIdx.x / 12;
    const int nh = blockIdx.x - bi * 12;
    const int wid = bi & 63;
    const int wh = wid >> 3, ww = wid & 7;
    const int b  = bi >> 6;
    const int tid = threadIdx.x;

    __shared__ __hip_bfloat16 sWin[49 * 384];  // 37632 B
    __shared__ __hip_bfloat16 sQ[49 * 32];
    __shared__ __hip_bfloat16 sK[49 * 32];
    __shared__ __hip_bfloat16 sV[49 * 32];
    __shared__ float sS[49 * 49];
    __shared__ float sBias[169];
    __shared__ float sG[384], sB[384];
    __shared__ float sMean[49], sRstd[49];
    __shared__ int   sTok[49];
    __shared__ unsigned char sGrp[49];

    for (int idx = tid; idx < 384; idx += 256) { sG[idx] = ln1_g[idx]; sB[idx] = ln1_b[idx]; }
    for (int idx = tid; idx < 169; idx += 256) sBias[idx] = rel_bias[idx * 12 + nh];
    if (tid < 49) {
        int r = tid / 7, c = tid - (tid / 7) * 7;
        int sh = wh * 7 + r + 3; if (sh >= 56) sh -= 56;
        int sw = ww * 7 + c + 3; if (sw >= 56) sw -= 56;
        int tok = b * 3136 + sh * 56 + sw;
        sTok[tid]  = tok;
        sMean[tid] = ln1s[2 * tok];
        sRstd[tid] = ln1s[2 * tok + 1];
        int gh = (wh == 7) ? ((r < 4) ? 1 : 2) : 0;
        int gw = (ww == 7) ? ((c < 4) ? 1 : 2) : 0;
        sGrp[tid] = (unsigned char)(gh * 3 + gw);
    }
    __syncthreads();

    // gather + LN1 -> sWin (bf16)
    for (int idx = tid; idx < 49 * 384; idx += 256) {
        int n = idx / 384, ch = idx - n * 384;
        float f = x[(size_t)sTok[n] * 384 + ch];
        sWin[idx] = f2bf((f - sMean[n]) * sRstd[n] * sG[ch] + sB[ch]);
    }
    __syncthreads();

    // qkv: 49 rows x 96 cols (q|k|v for this head), K=384
    for (int idx = tid; idx < 49 * 96; idx += 256) {
        int i = idx / 96, col = idx - i * 96;
        int s3 = col >> 5, d = col & 31;
        int cw = s3 * 384 + nh * 32 + d;
        float acc = qkv_b[cw];
        const __hip_bfloat16* arow = sWin + i * 384;
#pragma unroll 4
        for (int k0 = 0; k0 < 384; ++k0)
            acc += bf2f(arow[k0]) * qkv_w[(size_t)k0 * 1152 + cw];
        if (s3 == 0)      sQ[i * 32 + d] = f2bf(acc * 0.17677669529663689f);
        else if (s3 == 1) sK[i * 32 + d] = f2bf(acc);
        else              sV[i * 32 + d] = f2bf(acc);
    }
    __syncthreads();

    // scores + rel-bias + shift-mask
    for (int idx = tid; idx < 49 * 49; idx += 256) {
        int i = idx / 49, j = idx - i * 49;
        float acc = 0.f;
#pragma unroll
        for (int d = 0; d < 32; ++d)
            acc += bf2f(sQ[i * 32 + d]) * bf2f(sK[j * 32 + d]);
        int ri = i / 7, ci = i - ri * 7;
        int rj = j / 7, cj = j - rj * 7;
        float bias = sBias[(ri - rj + 6) * 13 + (ci - cj + 6)];
        float msk = (sGrp[i] == sGrp[j]) ? 0.f : -100.f;
        sS[idx] = acc + bias + msk;
    }
    __syncthreads();

    // softmax per row
    if (tid < 49) {
        float mx = -1e30f;
        for (int j = 0; j < 49; ++j) mx = fmaxf(mx, sS[tid * 49 + j]);
        float sum = 0.f;
        for (int j = 0; j < 49; ++j) {
            float e = expf(sS[tid * 49 + j] - mx);
            sS[tid * 49 + j] = e; sum += e;
        }
        float inv = 1.f / sum;
        for (int j = 0; j < 49; ++j) sS[tid * 49 + j] *= inv;
    }
    __syncthreads();

    // out = P @ V
    __hip_bfloat16* dst = attn_out + (size_t)bi * 49 * 384 + nh * 32;
    for (int idx = tid; idx < 49 * 32; idx += 256) {
        int i = idx >> 5, d = idx & 31;
        float acc = 0.f;
#pragma unroll 7
        for (int j = 0; j < 49; ++j)
            acc += sS[i * 49 + j] * bf2f(sV[j * 32 + d]);
        dst[(size_t)i * 384 + d] = f2bf(acc);
    }
}

// ---------------- GEMM 64x64x16 tiles, f32 acc; A bf16, B f32 --------------------
// MODE 0: proj  -> window-reverse+roll scatter + residual(x f32) -> bf16 xmid
// MODE 1: fc1 (LN2 applied to A on load) -> gelu -> bf16 h
// MODE 2: fc2   -> gelu -> + resbuf(bf16) -> f32 out rows [m_base..)
template<int MODE>
__global__ __launch_bounds__(256)
void gemm_ep(const __hip_bfloat16* __restrict__ A,   // M x K (chunk-local)
             const float* __restrict__ Bw,           // K x N
             const float* __restrict__ bias,         // N
             const float* __restrict__ x_in,         // MODE0 residual (f32, x-layout)
             const float* __restrict__ lnst,         // MODE1 stats, chunk base (2/row)
             const float* __restrict__ ln_g,
             const float* __restrict__ ln_b,
             const __hip_bfloat16* __restrict__ resb, // MODE2 residual (chunk-local)
             __hip_bfloat16* __restrict__ out_h,     // MODE0/1
             float* __restrict__ out_f,              // MODE2
             int M, int N, int K, int m_base)
{
    __shared__ float As[16][64];
    __shared__ float Bs[16][65];
    const int tid = threadIdx.x;
    const int tx = tid & 15, ty = tid >> 4;
    const int bm = blockIdx.y, bn = blockIdx.x;
    float acc[4][4] = {{0.f}};
    const int arow = tid >> 2, akc = (tid & 3) << 2;
    const int brow = tid >> 4, bcc = (tid & 15) << 2;

    float lm = 0.f, lr = 0.f;
    if (MODE == 1) {
        int r = bm * 64 + arow;
        lm = lnst[2 * r]; lr = lnst[2 * r + 1];
    }

    for (int kk = 0; kk < K; kk += 16) {
        const __hip_bfloat16* ap = A + (size_t)(bm * 64 + arow) * K + kk + akc;
#pragma unroll
        for (int u = 0; u < 4; ++u) {
            float v = bf2f(ap[u]);
            if (MODE == 1) {
                int k = kk + akc + u;
                v = (v - lm) * lr * ln_g[k] + ln_b[k];
            }
            As[akc + u][arow] = v;
        }
        const float* bp = Bw + (size_t)(kk + brow) * N + bn * 64 + bcc;
#pragma unroll
        for (int u = 0; u < 4; ++u) Bs[brow][bcc + u] = bp[u];
        __syncthreads();
#pragma unroll
        for (int k = 0; k < 16; ++k) {
            float a0 = As[k][ty * 4 + 0], a1 = As[k][ty * 4 + 1];
            float a2 = As[k][ty * 4 + 2], a3 = As[k][ty * 4 + 3];
            float b0 = Bs[k][tx * 4 + 0], b1 = Bs[k][tx * 4 + 1];
            float b2 = Bs[k][tx * 4 + 2], b3 = Bs[k][tx * 4 + 3];
            acc[0][0] += a0 * b0; acc[0][1] += a0 * b1; acc[0][2] += a0 * b2; acc[0][3] += a0 * b3;
            acc[1][0] += a1 * b0; acc[1][1] += a1 * b1; acc[1][2] += a1 * b2; acc[1][3] += a1 * b3;
            acc[2][0] += a2 * b0; acc[2][1] += a2 * b1; acc[2][2] += a2 * b2; acc[2][3] += a2 * b3;
            acc[3][0] += a3 * b0; acc[3][1] += a3 * b1; acc[3][2] += a3 * b2; acc[3][3] += a3 * b3;
        }
        __syncthreads();
    }

#pragma unroll
    for (int i = 0; i < 4; ++i) {
        int m = bm * 64 + ty * 4 + i;     // chunk-local row
        if (MODE == 0) {
            int gm = m;                    // window-token row (full M here)
            int biw = gm / 49, n_ = gm - biw * 49;
            int b_ = biw >> 6, wid = biw & 63;
            int wh = wid >> 3, ww = wid & 7;
            int r = n_ / 7, c = n_ - r * 7;
            int h = wh * 7 + r + 3; if (h >= 56) h -= 56;
            int w = ww * 7 + c + 3; if (w >= 56) w -= 56;
            size_t drow = (size_t)(b_ * 3136 + h * 56 + w) * 384;
#pragma unroll
            for (int j = 0; j < 4; ++j) {
                int nc = bn * 64 + tx * 4 + j;
                out_h[drow + nc] = f2bf(x_in[drow + nc] + acc[i][j] + bias[nc]);
            }
        } else if (MODE == 1) {
            size_t o = (size_t)m * N;
#pragma unroll
            for (int j = 0; j < 4; ++j) {
                int nc = bn * 64 + tx * 4 + j;
                out_h[o + nc] = f2bf(gelu_exact(acc[i][j] + bias[nc]));
            }
        } else {
            size_t og = (size_t)(m_base + m) * 384;
            size_t ol = (size_t)m * 384;
#pragma unroll
            for (int j = 0; j < 4; ++j) {
                int nc = bn * 64 + tx * 4 + j;
                out_f[og + nc] = bf2f(resb[ol + nc]) + gelu_exact(acc[i][j] + bias[nc]);
            }
        }
    }
}

extern "C" void kernel_launch(void* const* d_in, const int* in_sizes, int n_in,
                              void* d_out, int out_size, void* d_ws, size_t ws_size,
                              hipStream_t stream)
{
    (void)in_sizes; (void)n_in; (void)out_size; (void)ws_size;
    const float* x      = (const float*)d_in[0];
    const float* ln1_g  = (const float*)d_in[1];
    const float* ln1_b  = (const float*)d_in[2];
    const float* qkv_w  = (const float*)d_in[3];
    const float* qkv_b  = (const float*)d_in[4];
    const float* rel_b  = (const float*)d_in[5];
    const float* proj_w = (const float*)d_in[6];
    const float* proj_b = (const float*)d_in[7];
    const float* ln2_g  = (const float*)d_in[8];
    const float* ln2_b  = (const float*)d_in[9];
    const float* fc1_w  = (const float*)d_in[10];
    const float* fc1_b  = (const float*)d_in[11];
    const float* fc2_w  = (const float*)d_in[12];
    const float* fc2_b  = (const float*)d_in[13];
    float* out = (float*)d_out;

    __hip_bfloat16* aout = (__hip_bfloat16*)d_out;                      // H0: attnout
    __hip_bfloat16* xmid = (__hip_bfloat16*)((char*)d_out + 77070336);  // H1: residual

    char* ws = (char*)d_ws;
    float* ln1s = (float*)ws;                                  //   802,816 B
    float* ln2s = (float*)(ws + 802816);                       //   802,816 B
    __hip_bfloat16* resb = (__hip_bfloat16*)(ws + 1605632);    // 9,633,792 B
    __hip_bfloat16* hbuf = (__hip_bfloat16*)(ws + 11239424);   // 38,535,168 B

    // K0: LN1 stats on x
    ln_stats_kernel<float><<<25088, 256, 0, stream>>>(x, ln1s);
    // K2: fused LN1-gather + qkv + attention -> aout (H0)
    attn_kernel<<<2048 * 12, 256, 0, stream>>>(x, ln1s, ln1_g, ln1_b,
                                               qkv_w, qkv_b, rel_b, aout);
    // K3: proj + window-reverse + roll + residual -> xmid (H1)
    gemm_ep<0><<<dim3(6, 1568), 256, 0, stream>>>(
        aout, proj_w, proj_b, x, nullptr, nullptr, nullptr, nullptr,
        xmid, nullptr, 100352, 384, 384, 0);
    // K4: LN2 stats on xmid
    ln_stats_kernel<__hip_bfloat16><<<25088, 256, 0, stream>>>(xmid, ln2s);

    // MLP in 8 chunks of 12544 rows. Final f32 writes progressively overwrite
    // d_out; schedule verified stomp-free: chunk c stomps xmid rows
    // [25088(c-4), +25088), all consumed by chunks <= c; same-chunk residual
    // is read from the resb copy, never from xmid.
    for (int c = 0; c < 8; ++c) {
        int mb = c * 12544;
        gemm_ep<1><<<dim3(24, 196), 256, 0, stream>>>(
            xmid + (size_t)mb * 384, fc1_w, fc1_b, nullptr,
            ln2s + 2 * (size_t)mb, ln2_g, ln2_b, nullptr,
            hbuf, nullptr, 12544, 1536, 384, 0);
        hipMemcpyAsync(resb, xmid + (size_t)mb * 384, (size_t)12544 * 384 * 2,
                       hipMemcpyDeviceToDevice, stream);
        gemm_ep<2><<<dim3(6, 196), 256, 0, stream>>>(
            hbuf, fc2_w, fc2_b, nullptr, nullptr, nullptr, nullptr, resb,
            nullptr, out, 12544, 384, 1536, mb);
    }
}